// Round 4
// baseline (68.119 us; speedup 1.0000x reference)
//
#include <hip/hip_runtime.h>

// Problem shape (fixed by reference setup_inputs):
//   bert_emb:    [B=4, Lp=256, D=768] fp32
//   pieces2word: [B=4, Lw=200, Lp=256] int32 (0/1)
//   out:         [B=4, Lw=200, D=768] fp32
// out[b,w,d] = max over {p : mask[b,w,p]!=0} of emb[b,p,d], else global min(emb).
//
// R14 — W_=10 at float4 (emb streamed 20x instead of 40x).
//  R13 post-mortem: VALU (3.0us/SIMD) and SALU (2.0us/CU) cuts both paid
//  partially -> multiple co-equal overlapping terms. Largest remaining:
//  L2 read stream 480 blocks x 256 KB = 123 MB ~ 3.6 us. W=10 halves it
//  (240 x 256 KB = 61 MB ~ 1.8 us) while total VALU/SALU per CU are
//  invariant in W. Grid 240 <= 256 CUs: perfect balance, 1 block/CU
//  (R13's 1.875 blocks/CU makespan imbalance disappears).
//  - 240 blocks x 512 threads, 2 waves/SIMD; ~960 cy merge-VALU per
//    unroll-8 batch self-hides L2 latency.
//  - Merge restructured vs R8's failed W=10: TWO 5-word LDS passes
//    (sacc 40 KB, 3 barriers) instead of one 80 KB pass.
//  - Keeps R12/R13 v_max3 pair-merge (1.5 VALU/elem) and float4 gating
//    (one VCC per mask bit covers 4 cndmasks).
//  acc init = -inf bit-exact; empty-mask word -> global-min fallback.

#define B_  4
#define LP_ 256
#define LW_ 200
#define D_  768
#define D4_ (D_ / 4)              // 192 float4 per row
#define CHUNKS 3                  // 3 chunks x 256 floats (1 float4 per lane)
#define W_  10                    // words per block
#define HALFW 5                   // words merged per LDS pass
#define WG_ (LW_ / W_)            // 20 word-groups
#define NBLK (B_ * CHUNKS * WG_)  // 240 blocks
#define SEGS 8                    // waves (piece segments) per block
#define PPS 32                    // pieces per segment

__global__ __launch_bounds__(512) void word_max_scan(
    const float* __restrict__ emb, const int* __restrict__ p2w,
    float* __restrict__ out)
{
    const int blk   = blockIdx.x;
    const int wg    = blk % WG_;
    const int rest  = blk / WG_;
    const int chunk = rest % CHUNKS;
    const int b     = rest / CHUNKS;
    const int lane  = threadIdx.x & 63;
    const int s     = threadIdx.x >> 6;     // piece segment 0..7
    const int w0    = wg * W_;

    // Each wave ballots a 32-bit mask for its 32 pieces, per word.
    unsigned int m[W_];
    const int pc = s * PPS + (lane & 31);
    #pragma unroll
    for (int j = 0; j < W_; ++j) {
        const int* mrow = p2w + (b * LW_ + w0 + j) * LP_;
        m[j] = (unsigned int)__ballot((lane < 32) && (mrow[pc] != 0));
    }

    const float ninf = __uint_as_float(0xFF800000u);
    float4 acc[W_];
    #pragma unroll
    for (int j = 0; j < W_; ++j) acc[j] = make_float4(ninf, ninf, ninf, ninf);

    // Wave's row stream: rows [32s, 32s+32), column = chunk*64 + lane (float4).
    const float4* rps = (const float4*)(emb + (size_t)b * LP_ * D_)
                        + chunk * 64 + lane + (size_t)(s * PPS) * D4_;

    #pragma unroll
    for (int g = 0; g < PPS; g += 8) {
        float4 v[8];
        #pragma unroll
        for (int k = 0; k < 8; ++k)
            v[k] = rps[(size_t)(g + k) * D4_];
        #pragma unroll
        for (int k = 0; k < 8; k += 2) {
            #pragma unroll
            for (int j = 0; j < W_; ++j) {
                const bool b0 = (m[j] >> (g + k))     & 1u;  // uniform
                const bool b1 = (m[j] >> (g + k + 1)) & 1u;  // uniform
                // One VCC per bit gates FOUR cndmasks (amortized SALU).
                float sx0 = b0 ? v[k].x     : ninf;
                float sy0 = b0 ? v[k].y     : ninf;
                float sz0 = b0 ? v[k].z     : ninf;
                float sw0 = b0 ? v[k].w     : ninf;
                float sx1 = b1 ? v[k + 1].x : ninf;
                float sy1 = b1 ? v[k + 1].y : ninf;
                float sz1 = b1 ? v[k + 1].z : ninf;
                float sw1 = b1 ? v[k + 1].w : ninf;
                asm("v_max3_f32 %0, %1, %2, %3"
                    : "=v"(acc[j].x) : "v"(acc[j].x), "v"(sx0), "v"(sx1));
                asm("v_max3_f32 %0, %1, %2, %3"
                    : "=v"(acc[j].y) : "v"(acc[j].y), "v"(sy0), "v"(sy1));
                asm("v_max3_f32 %0, %1, %2, %3"
                    : "=v"(acc[j].z) : "v"(acc[j].z), "v"(sz0), "v"(sz1));
                asm("v_max3_f32 %0, %1, %2, %3"
                    : "=v"(acc[j].w) : "v"(acc[j].w), "v"(sw0), "v"(sw1));
            }
        }
    }

    // Merge the 8 segments via LDS in TWO passes of HALFW words each
    // (sacc = 8 x 5 x 64 x 16B = 40 KB; 80 KB single-pass would be too big).
    __shared__ float4 sacc[SEGS][HALFW][64];
    __shared__ unsigned int smask[SEGS][W_];
    if (lane == 0) {
        #pragma unroll
        for (int j = 0; j < W_; ++j) smask[s][j] = m[j];
    }

    #pragma unroll
    for (int half = 0; half < 2; ++half) {
        if (half) __syncthreads();   // readers of pass 0 done before overwrite
        #pragma unroll
        for (int j = 0; j < HALFW; ++j)
            sacc[s][j][lane] = acc[half * HALFW + j];
        __syncthreads();

        // Wave s (< HALFW) finalizes word half*HALFW + s.
        if (s < HALFW) {
            const int j = half * HALFW + s;
            float4 r = sacc[0][s][lane];
            #pragma unroll
            for (int seg = 1; seg < SEGS; ++seg) {
                r.x = fmaxf(r.x, sacc[seg][s][lane].x);
                r.y = fmaxf(r.y, sacc[seg][s][lane].y);
                r.z = fmaxf(r.z, sacc[seg][s][lane].z);
                r.w = fmaxf(r.w, sacc[seg][s][lane].w);
            }
            unsigned int om = 0;
            #pragma unroll
            for (int seg = 0; seg < SEGS; ++seg) om |= smask[seg][j];

            if (om == 0u) {
                // Never taken for the fixed inputs; correct fallback =
                // global min over ALL of emb (reference min_value).
                const float4* x = (const float4*)emb;
                const int n4 = (B_ * LP_ * D_) / 4;
                float mn = __uint_as_float(0x7F800000u);  // +inf
                for (int i = lane; i < n4; i += 64) {
                    float4 vv = x[i];
                    mn = fminf(mn, fminf(fminf(vv.x, vv.y), fminf(vv.z, vv.w)));
                }
                #pragma unroll
                for (int off = 32; off > 0; off >>= 1)
                    mn = fminf(mn, __shfl_down(mn, off, 64));
                mn = __shfl(mn, 0, 64);
                r = make_float4(mn, mn, mn, mn);
            }

            float4* op = (float4*)out + (size_t)(b * LW_ + w0 + j) * D4_
                         + chunk * 64 + lane;
            *op = r;
        }
    }
}

extern "C" void kernel_launch(void* const* d_in, const int* in_sizes, int n_in,
                              void* d_out, int out_size, void* d_ws, size_t ws_size,
                              hipStream_t stream) {
    const float* emb = (const float*)d_in[0];
    const int*   p2w = (const int*)d_in[1];
    float*       out = (float*)d_out;
    (void)d_ws; (void)ws_size;

    word_max_scan<<<NBLK, 512, 0, stream>>>(emb, p2w, out);
}